// Round 9
// baseline (274.410 us; speedup 1.0000x reference)
//
#include <hip/hip_runtime.h>

#define NB    4096
#define SEQ   64
#define DIM   128
#define NHEAD 8
#define ATTD  32
#define HKC   256
#define SCALE 0.17677669529663687f
#define LOG2E 1.4426950408889634f

typedef __bf16 bf16_t;
typedef __bf16 bf16x8 __attribute__((ext_vector_type(8)));
typedef __bf16 bf16x4 __attribute__((ext_vector_type(4)));
typedef float  f32x4  __attribute__((ext_vector_type(4)));
typedef unsigned int u32;

// native casts -> compiler emits v_cvt_pk_bf16_f32 (RNE), far fewer VALU ops
static __device__ __forceinline__ u32 pkbf(float a, float b) {
  unsigned short ua = __builtin_bit_cast(unsigned short, (__bf16)a);
  unsigned short ub = __builtin_bit_cast(unsigned short, (__bf16)b);
  return (u32)ua | ((u32)ub << 16);
}

// XOR swizzles on element index. Masks use bits >=3 only where b128 reads land
// (X/V/P rows), bits >=3 on 32-wide rows (W) too so 16B blocks stay contiguous.
#define XSWZ(r, c) (((r) << 7) + ((c) ^ (((r) & 7) << 3)))   // Xb: 64x128
#define WSWZ(r, c) (((r) << 5) + ((c) ^ (((r) & 3) << 3)))   // Kt/Qt: 64x32
#define VSWZ(r, c) (((r) << 6) + ((c) ^ (((r) & 7) << 3)))   // Vt: 32x64
#define PSWZ(r, c) (((r) << 6) + ((c) ^ (((r) & 7) << 3)))   // Pt: 16x64

// ws layout (bf16): [0:32768) WqT[c][d] (pre-scaled by SCALE*log2e),
// [32768:65536) WkT, [65536:98304) WvT, [98304:131072) WresT.
__global__ void prep_weights(const float* __restrict__ Wq,
                             const float* __restrict__ Wk,
                             const float* __restrict__ Wv,
                             const float* __restrict__ Wr,
                             bf16_t* __restrict__ ws) {
  int idx = blockIdx.x * 256 + threadIdx.x;  // 0..131071
  int m = idx >> 15;
  int e = idx & 32767;
  int c = e >> 7;
  int d = e & 127;
  float v;
  if (m == 0)      v = Wq[((c >> 5) * DIM + d) * ATTD + (c & 31)] * (SCALE * LOG2E);
  else if (m == 1) v = Wk[((c >> 5) * DIM + d) * ATTD + (c & 31)];
  else if (m == 2) v = Wv[((c >> 5) * DIM + d) * ATTD + (c & 31)];
  else             v = Wr[d * HKC + c];
  ws[idx] = (bf16_t)v;
}

// One block per batch; 4 waves; wave w handles heads {2w,2w+1}.
// LDS 32768 B: swizzled X tile + ONE 4 KB per-wave scratch time-shared as
// Kt -> Vt -> Qt -> Pt (wave-private, in-order DS => no barriers).
// Phase A: {K,V} share X frags; Phase B: {Q,res} share X frags.
// All D-layout->frag conversions via LDS round-trip (merge2/shuffles deleted).
__launch_bounds__(256, 3)
__global__ void fused_attn(const float* __restrict__ xg,
                           const bf16_t* __restrict__ ws,
                           float* __restrict__ outg) {
  __shared__ bf16_t Xb[64 * 128];
  __shared__ bf16_t VP[4][2048];   // 4 KB per-wave scratch

  const int t  = threadIdx.x;
  const int w  = t >> 6;
  const int l  = t & 63;
  const int lo = l & 15;
  const int g  = l >> 4;
  const int b  = blockIdx.x;

  bf16_t* const vp = VP[w];

  { // stage X -> LDS (bf16, swizzled)
    const float* xb = xg + (size_t)b * (SEQ * DIM);
#pragma unroll
    for (int i = 0; i < 8; ++i) {
      int idx = i * 1024 + t * 4;
      float4 v = *(const float4*)(xb + idx);
      bf16x4 p;
      p[0] = (bf16_t)v.x; p[1] = (bf16_t)v.y; p[2] = (bf16_t)v.z; p[3] = (bf16_t)v.w;
      *(bf16x4*)&Xb[XSWZ(idx >> 7, idx & 127)] = p;
    }
  }
  __syncthreads();

  const bf16_t* wsq = ws;
  const bf16_t* wsk = ws + 32768;
  const bf16_t* wsv = ws + 65536;
  const bf16_t* wsr = ws + 98304;
  float* ob = outg + (size_t)b * (SEQ * HKC);
  const f32x4 z4 = {0.f, 0.f, 0.f, 0.f};

#pragma unroll
  for (int hh = 0; hh < 2; ++hh) {
    const int hc = w * 64 + hh * 32;  // weight col base == output col base

    // ================= Phase A: K^T and V share the X fragments =================
    f32x4 acck[2][4];   // [at][nt]: rows a, cols n
    f32x4 accv[4][2];   // [nt][ct]: rows n, cols c
#pragma unroll
    for (int i = 0; i < 2; ++i)
#pragma unroll
      for (int j = 0; j < 4; ++j) acck[i][j] = z4;
#pragma unroll
    for (int i = 0; i < 4; ++i)
#pragma unroll
      for (int j = 0; j < 2; ++j) accv[i][j] = z4;
#pragma unroll
    for (int kk = 0; kk < 4; ++kk) {
      bf16x8 bx[4], awk[2], bwv[2];
#pragma unroll
      for (int nt = 0; nt < 4; ++nt)
        bx[nt] = *(const bf16x8*)&Xb[XSWZ(nt * 16 + lo, kk * 32 + g * 8)];
#pragma unroll
      for (int at = 0; at < 2; ++at)
        awk[at] = *(const bf16x8*)(wsk + (hc + at * 16 + lo) * DIM + kk * 32 + g * 8);
#pragma unroll
      for (int ct = 0; ct < 2; ++ct)
        bwv[ct] = *(const bf16x8*)(wsv + (hc + ct * 16 + lo) * DIM + kk * 32 + g * 8);
#pragma unroll
      for (int at = 0; at < 2; ++at)
#pragma unroll
        for (int nt = 0; nt < 4; ++nt)
          acck[at][nt] = __builtin_amdgcn_mfma_f32_16x16x32_bf16(awk[at], bx[nt], acck[at][nt], 0, 0, 0);
#pragma unroll
      for (int nt = 0; nt < 4; ++nt)
#pragma unroll
        for (int ct = 0; ct < 2; ++ct)
          accv[nt][ct] = __builtin_amdgcn_mfma_f32_16x16x32_bf16(bx[nt], bwv[ct], accv[nt][ct], 0, 0, 0);
    }

    // ---- K -> kf via LDS (Kt[n:64][a:32]) ----
#pragma unroll
    for (int at = 0; at < 2; ++at)
#pragma unroll
      for (int nt = 0; nt < 4; ++nt) {
        uint2 d;
        d.x = pkbf(acck[at][nt][0], acck[at][nt][1]);
        d.y = pkbf(acck[at][nt][2], acck[at][nt][3]);
        *(uint2*)&vp[WSWZ(nt * 16 + lo, at * 16 + 4 * g)] = d;
      }
    bf16x8 kf[4];  // A-frags for S^T: row n = lo, k = a = 8g+e
#pragma unroll
    for (int nt = 0; nt < 4; ++nt)
      kf[nt] = *(const bf16x8*)&vp[WSWZ(nt * 16 + lo, 8 * g)];

    // ---- V -> vf via LDS (Vt[c:32][n:64], overwrites Kt region) ----
#pragma unroll
    for (int nt = 0; nt < 4; ++nt)
#pragma unroll
      for (int ct = 0; ct < 2; ++ct) {
        uint2 d;
        d.x = pkbf(accv[nt][ct][0], accv[nt][ct][1]);
        d.y = pkbf(accv[nt][ct][2], accv[nt][ct][3]);
        *(uint2*)&vp[VSWZ(ct * 16 + lo, nt * 16 + 4 * g)] = d;
      }
    bf16x8 vf[2][2];  // B-frags: col c = lo, k = n
#pragma unroll
    for (int ct = 0; ct < 2; ++ct)
#pragma unroll
      for (int kk2 = 0; kk2 < 2; ++kk2)
        vf[ct][kk2] = *(const bf16x8*)&vp[VSWZ(ct * 16 + lo, kk2 * 32 + g * 8)];

    // ================= Phase B: Q^T and res^T share the X fragments =================
    f32x4 accq[2][4];   // [at][mt]: rows a, cols m
    f32x4 accr[2][4];   // [ct][mt]: rows c, cols m  (residual, later += PV*rinv)
#pragma unroll
    for (int i = 0; i < 2; ++i)
#pragma unroll
      for (int j = 0; j < 4; ++j) { accq[i][j] = z4; accr[i][j] = z4; }
#pragma unroll
    for (int kk = 0; kk < 4; ++kk) {
      bf16x8 bx[4], awq[2], awr[2];
#pragma unroll
      for (int mt = 0; mt < 4; ++mt)
        bx[mt] = *(const bf16x8*)&Xb[XSWZ(mt * 16 + lo, kk * 32 + g * 8)];
#pragma unroll
      for (int at = 0; at < 2; ++at)
        awq[at] = *(const bf16x8*)(wsq + (hc + at * 16 + lo) * DIM + kk * 32 + g * 8);
#pragma unroll
      for (int ct = 0; ct < 2; ++ct)
        awr[ct] = *(const bf16x8*)(wsr + (hc + ct * 16 + lo) * DIM + kk * 32 + g * 8);
#pragma unroll
      for (int at = 0; at < 2; ++at)
#pragma unroll
        for (int mt = 0; mt < 4; ++mt)
          accq[at][mt] = __builtin_amdgcn_mfma_f32_16x16x32_bf16(awq[at], bx[mt], accq[at][mt], 0, 0, 0);
#pragma unroll
      for (int ct = 0; ct < 2; ++ct)
#pragma unroll
        for (int mt = 0; mt < 4; ++mt)
          accr[ct][mt] = __builtin_amdgcn_mfma_f32_16x16x32_bf16(awr[ct], bx[mt], accr[ct][mt], 0, 0, 0);
    }

    // ---- Q -> qf via LDS (Qt[m:64][a:32], overwrites Vt region) ----
#pragma unroll
    for (int at = 0; at < 2; ++at)
#pragma unroll
      for (int mt = 0; mt < 4; ++mt) {
        uint2 d;
        d.x = pkbf(accq[at][mt][0], accq[at][mt][1]);
        d.y = pkbf(accq[at][mt][2], accq[at][mt][3]);
        *(uint2*)&vp[WSWZ(mt * 16 + lo, at * 16 + 4 * g)] = d;
      }
    bf16x8 qf[4];  // B-frags for S^T: col m = lo, k = a = 8g+e
#pragma unroll
    for (int mt = 0; mt < 4; ++mt)
      qf[mt] = *(const bf16x8*)&vp[WSWZ(mt * 16 + lo, 8 * g)];

    // ========== Phase D: per mt: S^T, exp2, P^T via LDS, PV folded into accr ==========
#pragma unroll
    for (int mt = 0; mt < 4; ++mt) {
      f32x4 sv[4];
#pragma unroll
      for (int nt = 0; nt < 4; ++nt)
        sv[nt] = __builtin_amdgcn_mfma_f32_16x16x32_bf16(kf[nt], qf[mt], z4, 0, 0, 0);
      // E = 2^S (scores pre-scaled by log2e); no max-subtract (range-safe)
      float sum = 0.f;
#pragma unroll
      for (int nt = 0; nt < 4; ++nt)
#pragma unroll
        for (int j = 0; j < 4; ++j) {
          float e = __builtin_amdgcn_exp2f(sv[nt][j]);
          sv[nt][j] = e;
          sum += e;
        }
      // write unnormalized P^T slice (lane holds n = nt*16+4g+j, m = lo)
#pragma unroll
      for (int nt = 0; nt < 4; ++nt) {
        uint2 d;
        d.x = pkbf(sv[nt][0], sv[nt][1]);
        d.y = pkbf(sv[nt][2], sv[nt][3]);
        *(uint2*)&vp[PSWZ(lo, nt * 16 + 4 * g)] = d;
      }
      // sum reduce off the P path
      sum += __shfl_xor(sum, 16, 64);
      sum += __shfl_xor(sum, 32, 64);
      float rinv = __builtin_amdgcn_rcpf(sum);
      // read back as B-frags (col m = lo, k = n) and do PV
      bf16x8 pf0 = *(const bf16x8*)&vp[PSWZ(lo, g * 8)];
      bf16x8 pf1 = *(const bf16x8*)&vp[PSWZ(lo, 32 + g * 8)];
#pragma unroll
      for (int ct = 0; ct < 2; ++ct) {
        f32x4 a = __builtin_amdgcn_mfma_f32_16x16x32_bf16(vf[ct][0], pf0, z4, 0, 0, 0);
        a = __builtin_amdgcn_mfma_f32_16x16x32_bf16(vf[ct][1], pf1, a, 0, 0, 0);
#pragma unroll
        for (int j = 0; j < 4; ++j)
          accr[ct][mt][j] = fmaf(a[j], rinv, accr[ct][mt][j]);  // ctx/sum + res
      }
    }

    // ---- ReLU + float4 store: rows c = hc+ct*16+4g+j, col m = mt*16+lo ----
#pragma unroll
    for (int ct = 0; ct < 2; ++ct)
#pragma unroll
      for (int mt = 0; mt < 4; ++mt) {
        float4 o;
        o.x = fmaxf(accr[ct][mt][0], 0.f);
        o.y = fmaxf(accr[ct][mt][1], 0.f);
        o.z = fmaxf(accr[ct][mt][2], 0.f);
        o.w = fmaxf(accr[ct][mt][3], 0.f);
        *(float4*)(ob + (mt * 16 + lo) * HKC + hc + ct * 16 + 4 * g) = o;
      }
  }
}

extern "C" void kernel_launch(void* const* d_in, const int* in_sizes, int n_in,
                              void* d_out, int out_size, void* d_ws, size_t ws_size,
                              hipStream_t stream) {
  const float* x  = (const float*)d_in[0];
  const float* Wq = (const float*)d_in[1];
  const float* Wk = (const float*)d_in[2];
  const float* Wv = (const float*)d_in[3];
  const float* Wr = (const float*)d_in[4];
  bf16_t* ws = (bf16_t*)d_ws;
  float* out = (float*)d_out;

  prep_weights<<<512, 256, 0, stream>>>(Wq, Wk, Wv, Wr, ws);
  fused_attn<<<NB, 256, 0, stream>>>(x, ws, out);
}